// Round 1
// baseline (879.293 us; speedup 1.0000x reference)
//
#include <hip/hip_runtime.h>
#include <hip/hip_bf16.h>

// HeteroGCNConv: 3-layer GCN, N=100000, E=1600000, D=128, f32.
// Pipeline: deg histograms -> CSR build (scan) -> per layer {GEMM, gather-agg}.
// Workspace layout (bytes):
//   0        : float deg_src[N]
//   512K     : float deg_dst[N]
//   1024K    : int   counts[N]
//   1536K    : int   cursor[N]
//   2048K    : int   row_start[N+1]
//   2560K    : int   blockSums[<=512]
//   3M       : int   sorted_src[E]
//   10M      : float sorted_w[E]
//   17M      : float B0[N*128]        (ping-pong buffer with d_out)
// Total ~68.2 MB.

#define D128 128

__device__ __forceinline__ float elu1(float x) {
    return x > 0.f ? x : (expf(x) - 1.f);
}

__global__ __launch_bounds__(256) void build_deg(
    const int* __restrict__ src, const int* __restrict__ dst,
    const float* __restrict__ w,
    float* __restrict__ deg_src, float* __restrict__ deg_dst,
    int* __restrict__ counts, int E) {
    int e = blockIdx.x * 256 + threadIdx.x;
    if (e >= E) return;
    atomicAdd(&deg_src[src[e]], w[e]);
    atomicAdd(&deg_dst[dst[e]], w[e]);
    atomicAdd(&counts[dst[e]], 1);
}

// Per-block exclusive scan (256 elems), writes block totals.
__global__ __launch_bounds__(256) void scan_block(
    const int* __restrict__ counts, int* __restrict__ row_start,
    int* __restrict__ blockSums, int n) {
    __shared__ int tmp[256];
    int gid = blockIdx.x * 256 + threadIdx.x;
    int v = (gid < n) ? counts[gid] : 0;
    tmp[threadIdx.x] = v;
    __syncthreads();
    for (int off = 1; off < 256; off <<= 1) {
        int t = (threadIdx.x >= off) ? tmp[threadIdx.x - off] : 0;
        __syncthreads();
        tmp[threadIdx.x] += t;
        __syncthreads();
    }
    if (gid < n) row_start[gid] = tmp[threadIdx.x] - v;  // exclusive
    if (threadIdx.x == 255) blockSums[blockIdx.x] = tmp[255];
}

// Exclusive scan of block sums (nb <= 512), single block.
__global__ __launch_bounds__(512) void scan_sums(int* __restrict__ bsums, int nb) {
    __shared__ int tmp[512];
    int v = (threadIdx.x < nb) ? bsums[threadIdx.x] : 0;
    tmp[threadIdx.x] = v;
    __syncthreads();
    for (int off = 1; off < 512; off <<= 1) {
        int t = (threadIdx.x >= off) ? tmp[threadIdx.x - off] : 0;
        __syncthreads();
        tmp[threadIdx.x] += t;
        __syncthreads();
    }
    if (threadIdx.x < nb) bsums[threadIdx.x] = tmp[threadIdx.x] - v;  // exclusive
}

__global__ __launch_bounds__(256) void scan_add(
    int* __restrict__ row_start, const int* __restrict__ bsums, int n, int E) {
    int gid = blockIdx.x * 256 + threadIdx.x;
    if (gid < n) row_start[gid] += bsums[blockIdx.x];
    if (gid == 0) row_start[n] = E;
}

// Bucket edges by dst; compute normalized weight inline.
__global__ __launch_bounds__(256) void scatter_edges(
    const int* __restrict__ src, const int* __restrict__ dst,
    const float* __restrict__ w,
    const float* __restrict__ deg_src, const float* __restrict__ deg_dst,
    const int* __restrict__ row_start, int* __restrict__ cursor,
    int* __restrict__ ssrc, float* __restrict__ sw, int E) {
    int e = blockIdx.x * 256 + threadIdx.x;
    if (e >= E) return;
    int s = src[e], d = dst[e];
    int pos = row_start[d] + atomicAdd(&cursor[d], 1);
    ssrc[pos] = s;
    sw[pos] = w[e] * rsqrtf(deg_src[s] * deg_dst[d]);
}

// out[r] = A[r] @ W  (W is [128][128] row-major). Row-local => in-place safe.
// 16 rows staged in LDS per iter; thread (j = tid&127, rg = tid>>7) owns
// rows rg, rg+2, ..., rg+14 at column j.
#define GR 16
__global__ __launch_bounds__(256) void gemm128(
    const float* __restrict__ A, const float* __restrict__ W,
    float* __restrict__ out, int n, int nblk) {
    __shared__ float rows[GR][D128];
    const int tid = threadIdx.x;
    const int j = tid & 127;
    const int rg = tid >> 7;
    for (int rb = blockIdx.x; rb < nblk; rb += gridDim.x) {
        const int r0 = rb * GR;
        __syncthreads();  // protect rows[] from previous iteration's readers
        for (int f = tid; f < GR * 32; f += 256) {
            int rr = f >> 5, ch = f & 31;
            int grow = r0 + rr;
            float4 v = make_float4(0.f, 0.f, 0.f, 0.f);
            if (grow < n) v = ((const float4*)(A + (size_t)grow * D128))[ch];
            ((float4*)&rows[rr][0])[ch] = v;
        }
        __syncthreads();
        float acc[8] = {0.f, 0.f, 0.f, 0.f, 0.f, 0.f, 0.f, 0.f};
        for (int k = 0; k < D128; k += 4) {
            float w0 = W[(k + 0) * D128 + j];
            float w1 = W[(k + 1) * D128 + j];
            float w2 = W[(k + 2) * D128 + j];
            float w3 = W[(k + 3) * D128 + j];
#pragma unroll
            for (int m = 0; m < 8; ++m) {
                float4 r = *((const float4*)&rows[rg + 2 * m][k]);
                acc[m] = fmaf(r.x, w0, acc[m]);
                acc[m] = fmaf(r.y, w1, acc[m]);
                acc[m] = fmaf(r.z, w2, acc[m]);
                acc[m] = fmaf(r.w, w3, acc[m]);
            }
        }
#pragma unroll
        for (int m = 0; m < 8; ++m) {
            int rr = r0 + rg + 2 * m;
            if (rr < n) out[(size_t)rr * D128 + j] = acc[m];
        }
    }
}

// One wave per dst node; 2 edges x 32 float4-chunks per iteration.
__global__ __launch_bounds__(256) void aggregate(
    const float* __restrict__ h, const int* __restrict__ rs,
    const int* __restrict__ ssrc, const float* __restrict__ sw,
    const float* __restrict__ bias, float* __restrict__ out, int n) {
    int wave = threadIdx.x >> 6;
    int lane = threadIdx.x & 63;
    int node = blockIdx.x * 4 + wave;
    if (node >= n) return;
    int beg = rs[node], end = rs[node + 1];
    int half = lane >> 5, c = lane & 31;
    float4 acc = make_float4(0.f, 0.f, 0.f, 0.f);
    for (int i = beg + half; i < end; i += 2) {
        int s = ssrc[i];
        float w = sw[i];
        float4 r = ((const float4*)(h + (size_t)s * D128))[c];
        acc.x = fmaf(r.x, w, acc.x);
        acc.y = fmaf(r.y, w, acc.y);
        acc.z = fmaf(r.z, w, acc.z);
        acc.w = fmaf(r.w, w, acc.w);
    }
    acc.x += __shfl_xor(acc.x, 32);
    acc.y += __shfl_xor(acc.y, 32);
    acc.z += __shfl_xor(acc.z, 32);
    acc.w += __shfl_xor(acc.w, 32);
    if (half == 0) {
        float4 bb = ((const float4*)bias)[c];
        float4 o;
        o.x = elu1(acc.x + bb.x);
        o.y = elu1(acc.y + bb.y);
        o.z = elu1(acc.z + bb.z);
        o.w = elu1(acc.w + bb.w);
        ((float4*)(out + (size_t)node * D128))[c] = o;
    }
}

extern "C" void kernel_launch(void* const* d_in, const int* in_sizes, int n_in,
                              void* d_out, int out_size, void* d_ws, size_t ws_size,
                              hipStream_t stream) {
    const float* x   = (const float*)d_in[0];
    const float* ew  = (const float*)d_in[1];
    const float* W   = (const float*)d_in[2];
    const float* b   = (const float*)d_in[3];
    const int*   src = (const int*)d_in[4];
    const int*   dst = (const int*)d_in[5];
    float* out = (float*)d_out;

    const int N = in_sizes[0] / D128;
    const int E = in_sizes[1];
    const int L = in_sizes[2] / (D128 * D128);

    char* ws = (char*)d_ws;
    float* deg_src = (float*)(ws + 0);
    float* deg_dst = (float*)(ws + (512 << 10));
    int*   counts  = (int*)(ws + (1024 << 10));
    int*   cursor  = (int*)(ws + (1536 << 10));
    int*   rstart  = (int*)(ws + (2048 << 10));
    int*   bsums   = (int*)(ws + (2560 << 10));
    int*   ssrc    = (int*)(ws + (3 << 20));
    float* sw      = (float*)(ws + (10 << 20));
    float* B0      = (float*)(ws + (17 << 20));

    // zero deg_src/deg_dst/counts/cursor in one shot
    hipMemsetAsync(ws, 0, 2048 << 10, stream);

    const int eb = (E + 255) / 256;
    const int sb = (N + 255) / 256;  // must be <= 512 (N <= 131072)

    build_deg<<<eb, 256, 0, stream>>>(src, dst, ew, deg_src, deg_dst, counts, E);
    scan_block<<<sb, 256, 0, stream>>>(counts, rstart, bsums, N);
    scan_sums<<<1, 512, 0, stream>>>(bsums, sb);
    scan_add<<<sb, 256, 0, stream>>>(rstart, bsums, N, E);
    scatter_edges<<<eb, 256, 0, stream>>>(src, dst, ew, deg_src, deg_dst,
                                          rstart, cursor, ssrc, sw, E);

    const int nblk = (N + GR - 1) / GR;
    const int gemm_grid = nblk < 2048 ? nblk : 2048;
    const int agg_grid = (N + 3) / 4;

    // layer 0: x --gemm--> B0 --agg--> out
    gemm128<<<gemm_grid, 256, 0, stream>>>(x, W, B0, N, nblk);
    aggregate<<<agg_grid, 256, 0, stream>>>(B0, rstart, ssrc, sw, b, out, N);
    if (L > 1) {
        // layer 1: out --gemm(in-place)--> out --agg--> B0
        gemm128<<<gemm_grid, 256, 0, stream>>>(out, W + D128 * D128, out, N, nblk);
        aggregate<<<agg_grid, 256, 0, stream>>>(out, rstart, ssrc, sw, b + D128, B0, N);
    }
    if (L > 2) {
        // layer 2: B0 --gemm(in-place)--> B0 --agg--> out
        gemm128<<<gemm_grid, 256, 0, stream>>>(B0, W + 2 * D128 * D128, B0, N, nblk);
        aggregate<<<agg_grid, 256, 0, stream>>>(B0, rstart, ssrc, sw, b + 2 * D128, out, N);
    }
}

// Round 2
// 794.760 us; speedup vs baseline: 1.1064x; 1.1064x over previous
//
#include <hip/hip_runtime.h>
#include <hip/hip_bf16.h>

// HeteroGCNConv: 3-layer GCN, N=100000, E=1600000, D=128, f32.
// Pipeline: deg histograms -> CSR build (scan) -> per layer {GEMM, gather-agg}.
// R1: pack counts+deg_dst into one 64b atomic (memory-side atomics cost
//     ~32B HBM write each); rcur=rstart copy kills row_start gather;
//     edata=int2{src,nw} single stream; aggregate unrolled x2.

#define D128 128

__device__ __forceinline__ float elu1(float x) {
    return x > 0.f ? x : (expf(x) - 1.f);
}

// packed[d] += (1<<48) | fix40(w);  deg_src[s] += w
__global__ __launch_bounds__(256) void build_deg(
    const int* __restrict__ src, const int* __restrict__ dst,
    const float* __restrict__ w,
    float* __restrict__ deg_src, unsigned long long* __restrict__ packed, int E) {
    int e = blockIdx.x * 256 + threadIdx.x;
    if (e >= E) return;
    float wv = w[e];
    atomicAdd(&deg_src[src[e]], wv);
    unsigned long long fx = (unsigned long long)(wv * 1.0995116277760e12f + 0.5f);
    atomicAdd(&packed[dst[e]], (1ULL << 48) | fx);
}

// Per-block exclusive scan (256 elems) over counts = packed>>48.
__global__ __launch_bounds__(256) void scan_block(
    const unsigned long long* __restrict__ packed, int* __restrict__ row_start,
    int* __restrict__ blockSums, int n) {
    __shared__ int tmp[256];
    int gid = blockIdx.x * 256 + threadIdx.x;
    int v = (gid < n) ? (int)(packed[gid] >> 48) : 0;
    tmp[threadIdx.x] = v;
    __syncthreads();
    for (int off = 1; off < 256; off <<= 1) {
        int t = (threadIdx.x >= off) ? tmp[threadIdx.x - off] : 0;
        __syncthreads();
        tmp[threadIdx.x] += t;
        __syncthreads();
    }
    if (gid < n) row_start[gid] = tmp[threadIdx.x] - v;  // exclusive
    if (threadIdx.x == 255) blockSums[blockIdx.x] = tmp[255];
}

__global__ __launch_bounds__(512) void scan_sums(int* __restrict__ bsums, int nb) {
    __shared__ int tmp[512];
    int v = (threadIdx.x < nb) ? bsums[threadIdx.x] : 0;
    tmp[threadIdx.x] = v;
    __syncthreads();
    for (int off = 1; off < 512; off <<= 1) {
        int t = (threadIdx.x >= off) ? tmp[threadIdx.x - off] : 0;
        __syncthreads();
        tmp[threadIdx.x] += t;
        __syncthreads();
    }
    if (threadIdx.x < nb) bsums[threadIdx.x] = tmp[threadIdx.x] - v;  // exclusive
}

__global__ __launch_bounds__(256) void scan_add(
    int* __restrict__ row_start, int* __restrict__ rcur,
    const int* __restrict__ bsums, int n, int E) {
    int gid = blockIdx.x * 256 + threadIdx.x;
    if (gid < n) {
        int v = row_start[gid] + bsums[blockIdx.x];
        row_start[gid] = v;
        rcur[gid] = v;
    }
    if (gid == 0) row_start[n] = E;
}

// Bucket edges by dst; normalized weight inline; single int2 stream out.
__global__ __launch_bounds__(256) void scatter_edges(
    const int* __restrict__ src, const int* __restrict__ dst,
    const float* __restrict__ w,
    const float* __restrict__ deg_src, const unsigned long long* __restrict__ packed,
    int* __restrict__ rcur, int2* __restrict__ edata, int E) {
    int e = blockIdx.x * 256 + threadIdx.x;
    if (e >= E) return;
    int s = src[e], d = dst[e];
    float degd = (float)(packed[d] & 0xFFFFFFFFFFFFULL) * 9.094947017729282e-13f;
    float nw = w[e] * rsqrtf(deg_src[s] * degd);
    int pos = atomicAdd(&rcur[d], 1);
    edata[pos] = make_int2(s, __float_as_int(nw));
}

// out[r] = A[r] @ W  (W is [128][128] row-major). Row-local => in-place safe.
#define GR 16
__global__ __launch_bounds__(256) void gemm128(
    const float* __restrict__ A, const float* __restrict__ W,
    float* __restrict__ out, int n, int nblk) {
    __shared__ float rows[GR][D128];
    const int tid = threadIdx.x;
    const int j = tid & 127;
    const int rg = tid >> 7;
    for (int rb = blockIdx.x; rb < nblk; rb += gridDim.x) {
        const int r0 = rb * GR;
        __syncthreads();  // protect rows[] from previous iteration's readers
        for (int f = tid; f < GR * 32; f += 256) {
            int rr = f >> 5, ch = f & 31;
            int grow = r0 + rr;
            float4 v = make_float4(0.f, 0.f, 0.f, 0.f);
            if (grow < n) v = ((const float4*)(A + (size_t)grow * D128))[ch];
            ((float4*)&rows[rr][0])[ch] = v;
        }
        __syncthreads();
        float acc[8] = {0.f, 0.f, 0.f, 0.f, 0.f, 0.f, 0.f, 0.f};
        for (int k = 0; k < D128; k += 4) {
            float w0 = W[(k + 0) * D128 + j];
            float w1 = W[(k + 1) * D128 + j];
            float w2 = W[(k + 2) * D128 + j];
            float w3 = W[(k + 3) * D128 + j];
#pragma unroll
            for (int m = 0; m < 8; ++m) {
                float4 r = *((const float4*)&rows[rg + 2 * m][k]);
                acc[m] = fmaf(r.x, w0, acc[m]);
                acc[m] = fmaf(r.y, w1, acc[m]);
                acc[m] = fmaf(r.z, w2, acc[m]);
                acc[m] = fmaf(r.w, w3, acc[m]);
            }
        }
#pragma unroll
        for (int m = 0; m < 8; ++m) {
            int rr = r0 + rg + 2 * m;
            if (rr < n) out[(size_t)rr * D128 + j] = acc[m];
        }
    }
}

// One wave per dst node; 2 edges x 32 float4-chunks per iter, unrolled x2.
__global__ __launch_bounds__(256) void aggregate(
    const float* __restrict__ h, const int* __restrict__ rs,
    const int2* __restrict__ edata,
    const float* __restrict__ bias, float* __restrict__ out, int n) {
    int wave = threadIdx.x >> 6;
    int lane = threadIdx.x & 63;
    int node = blockIdx.x * 4 + wave;
    if (node >= n) return;
    int beg = rs[node], end = rs[node + 1];
    int half = lane >> 5, c = lane & 31;
    float4 acc0 = make_float4(0.f, 0.f, 0.f, 0.f);
    float4 acc1 = make_float4(0.f, 0.f, 0.f, 0.f);
    int i = beg + half;
    for (; i + 2 < end; i += 4) {
        int2 e0 = edata[i];
        int2 e1 = edata[i + 2];
        float4 r0 = ((const float4*)(h + (size_t)e0.x * D128))[c];
        float4 r1 = ((const float4*)(h + (size_t)e1.x * D128))[c];
        float w0 = __int_as_float(e0.y), w1 = __int_as_float(e1.y);
        acc0.x = fmaf(r0.x, w0, acc0.x);
        acc0.y = fmaf(r0.y, w0, acc0.y);
        acc0.z = fmaf(r0.z, w0, acc0.z);
        acc0.w = fmaf(r0.w, w0, acc0.w);
        acc1.x = fmaf(r1.x, w1, acc1.x);
        acc1.y = fmaf(r1.y, w1, acc1.y);
        acc1.z = fmaf(r1.z, w1, acc1.z);
        acc1.w = fmaf(r1.w, w1, acc1.w);
    }
    if (i < end) {
        int2 e0 = edata[i];
        float4 r0 = ((const float4*)(h + (size_t)e0.x * D128))[c];
        float w0 = __int_as_float(e0.y);
        acc0.x = fmaf(r0.x, w0, acc0.x);
        acc0.y = fmaf(r0.y, w0, acc0.y);
        acc0.z = fmaf(r0.z, w0, acc0.z);
        acc0.w = fmaf(r0.w, w0, acc0.w);
    }
    acc0.x += acc1.x; acc0.y += acc1.y; acc0.z += acc1.z; acc0.w += acc1.w;
    acc0.x += __shfl_xor(acc0.x, 32);
    acc0.y += __shfl_xor(acc0.y, 32);
    acc0.z += __shfl_xor(acc0.z, 32);
    acc0.w += __shfl_xor(acc0.w, 32);
    if (half == 0) {
        float4 bb = ((const float4*)bias)[c];
        float4 o;
        o.x = elu1(acc0.x + bb.x);
        o.y = elu1(acc0.y + bb.y);
        o.z = elu1(acc0.z + bb.z);
        o.w = elu1(acc0.w + bb.w);
        ((float4*)(out + (size_t)node * D128))[c] = o;
    }
}

extern "C" void kernel_launch(void* const* d_in, const int* in_sizes, int n_in,
                              void* d_out, int out_size, void* d_ws, size_t ws_size,
                              hipStream_t stream) {
    const float* x   = (const float*)d_in[0];
    const float* ew  = (const float*)d_in[1];
    const float* W   = (const float*)d_in[2];
    const float* b   = (const float*)d_in[3];
    const int*   src = (const int*)d_in[4];
    const int*   dst = (const int*)d_in[5];
    float* out = (float*)d_out;

    const int N = in_sizes[0] / D128;
    const int E = in_sizes[1];
    const int L = in_sizes[2] / (D128 * D128);

    char* ws = (char*)d_ws;
    size_t off = 0;
    auto take = [&](size_t bytes) {
        void* p = ws + off;
        off = (off + bytes + 255) & ~(size_t)255;
        return p;
    };
    unsigned long long* packed = (unsigned long long*)take((size_t)N * 8);
    float* deg_src = (float*)take((size_t)N * 4);
    int*   rstart  = (int*)take((size_t)(N + 1) * 4);
    int*   rcur    = (int*)take((size_t)(N + 1) * 4);
    int*   bsums   = (int*)take(512 * 4);
    int2*  edata   = (int2*)take((size_t)E * 8);
    float* B0      = (float*)take((size_t)N * D128 * 4);

    // zero packed + deg_src (contiguous at base)
    hipMemsetAsync(ws, 0, (size_t)N * 12 + 512, stream);

    const int eb = (E + 255) / 256;
    const int sb = (N + 255) / 256;  // must be <= 512 (N <= 131072)

    build_deg<<<eb, 256, 0, stream>>>(src, dst, ew, deg_src, packed, E);
    scan_block<<<sb, 256, 0, stream>>>(packed, rstart, bsums, N);
    scan_sums<<<1, 512, 0, stream>>>(bsums, sb);
    scan_add<<<sb, 256, 0, stream>>>(rstart, rcur, bsums, N, E);
    scatter_edges<<<eb, 256, 0, stream>>>(src, dst, ew, deg_src, packed,
                                          rcur, edata, E);

    const int nblk = (N + GR - 1) / GR;
    const int gemm_grid = nblk < 2048 ? nblk : 2048;
    const int agg_grid = (N + 3) / 4;

    // layer 0: x --gemm--> B0 --agg--> out
    gemm128<<<gemm_grid, 256, 0, stream>>>(x, W, B0, N, nblk);
    aggregate<<<agg_grid, 256, 0, stream>>>(B0, rstart, edata, b, out, N);
    if (L > 1) {
        // layer 1: out --gemm(in-place)--> out --agg--> B0
        gemm128<<<gemm_grid, 256, 0, stream>>>(out, W + D128 * D128, out, N, nblk);
        aggregate<<<agg_grid, 256, 0, stream>>>(out, rstart, edata, b + D128, B0, N);
    }
    if (L > 2) {
        // layer 2: B0 --gemm(in-place)--> B0 --agg--> out
        gemm128<<<gemm_grid, 256, 0, stream>>>(B0, W + 2 * D128 * D128, B0, N, nblk);
        aggregate<<<agg_grid, 256, 0, stream>>>(B0, rstart, edata, b + 2 * D128, out, N);
    }
}

// Round 3
// 708.373 us; speedup vs baseline: 1.2413x; 1.1220x over previous
//
#include <hip/hip_runtime.h>
#include <hip/hip_bf16.h>

// HeteroGCNConv: 3-layer GCN, N=100000, E=1600000, D=128, f32.
// R2: CSR build via stable radix partition by dst>>8 (no global atomics on
//     the dst side). Remaining global atomics: deg_src histogram only.
//     pkey/pw alias B0 (dead before gemm0) to keep ws footprint ~66MB.

#define D128 128
#define PBLK 256          // partition blocks (pass A/C)
#define BUCKET_SHIFT 8
#define DCAP 7168         // staged edges per bucket in pass D (57KB LDS)

__device__ __forceinline__ float elu1(float x) {
    return x > 0.f ? x : (expf(x) - 1.f);
}

// deg_src[s] += w  (1.6M device atomics, ~32B HBM write each)
__global__ __launch_bounds__(256) void deg_src_hist(
    const int* __restrict__ src, const float* __restrict__ w,
    float* __restrict__ deg_src, int E) {
    int e = blockIdx.x * 256 + threadIdx.x;
    if (e >= E) return;
    atomicAdd(&deg_src[src[e]], w[e]);
}

// Pass A: per-block coarse-bucket histogram (LDS atomics), transposed store.
__global__ __launch_bounds__(256) void part_hist(
    const int* __restrict__ dst, int* __restrict__ histT,
    int E, int nb, int chunk) {
    extern __shared__ int sh[];  // nb ints
    for (int i = threadIdx.x; i < nb; i += 256) sh[i] = 0;
    __syncthreads();
    int b = blockIdx.x;
    int beg = b * chunk, end = min(E, beg + chunk);
    for (int e = beg + threadIdx.x; e < end; e += 256)
        atomicAdd(&sh[dst[e] >> BUCKET_SHIFT], 1);
    __syncthreads();
    for (int i = threadIdx.x; i < nb; i += 256) histT[i * PBLK + b] = sh[i];
}

// Generic hierarchical exclusive scan (n <= 131072).
__global__ __launch_bounds__(256) void scan_block(
    const int* __restrict__ in, int* __restrict__ out,
    int* __restrict__ blockSums, int n) {
    __shared__ int tmp[256];
    int gid = blockIdx.x * 256 + threadIdx.x;
    int v = (gid < n) ? in[gid] : 0;
    tmp[threadIdx.x] = v;
    __syncthreads();
    for (int off = 1; off < 256; off <<= 1) {
        int t = (threadIdx.x >= off) ? tmp[threadIdx.x - off] : 0;
        __syncthreads();
        tmp[threadIdx.x] += t;
        __syncthreads();
    }
    if (gid < n) out[gid] = tmp[threadIdx.x] - v;  // exclusive
    if (threadIdx.x == 255) blockSums[blockIdx.x] = tmp[255];
}

__global__ __launch_bounds__(512) void scan_sums(int* __restrict__ bsums, int nb) {
    __shared__ int tmp[512];
    int v = (threadIdx.x < nb) ? bsums[threadIdx.x] : 0;
    tmp[threadIdx.x] = v;
    __syncthreads();
    for (int off = 1; off < 512; off <<= 1) {
        int t = (threadIdx.x >= off) ? tmp[threadIdx.x - off] : 0;
        __syncthreads();
        tmp[threadIdx.x] += t;
        __syncthreads();
    }
    if (threadIdx.x < nb) bsums[threadIdx.x] = tmp[threadIdx.x] - v;  // exclusive
}

__global__ __launch_bounds__(256) void scan_add(
    int* __restrict__ out, const int* __restrict__ bsums, int n) {
    int gid = blockIdx.x * 256 + threadIdx.x;
    if (gid < n) out[gid] += bsums[blockIdx.x];
}

// Pass C: stable partition. Each (block,bucket) owns a private contiguous
// output range -> sequential per-stream writes -> L2 write-coalescing.
__global__ __launch_bounds__(256) void part_scatter(
    const int* __restrict__ src, const int* __restrict__ dst,
    const float* __restrict__ w, const int* __restrict__ offsT,
    unsigned int* __restrict__ pkey, float* __restrict__ pw,
    int E, int nb, int chunk) {
    extern __shared__ int cur[];  // nb ints
    int b = blockIdx.x;
    for (int i = threadIdx.x; i < nb; i += 256) cur[i] = offsT[i * PBLK + b];
    __syncthreads();
    int beg = b * chunk, end = min(E, beg + chunk);
    for (int e = beg + threadIdx.x; e < end; e += 256) {
        int d = dst[e];
        int k = d >> BUCKET_SHIFT;
        int pos = atomicAdd(&cur[k], 1);
        pkey[pos] = (unsigned)src[e] | ((unsigned)(d & 255) << 24);
        pw[pos] = w[e];
    }
}

// Pass D: one block per bucket. LDS histogram -> per-node counts + weighted
// in-degree; LDS scan -> row_start; reorder bucket edges; write edata{src,nw}.
__global__ __launch_bounds__(256) void bucket_build(
    const unsigned int* __restrict__ pkey, const float* __restrict__ pw,
    const int* __restrict__ offsT, const float* __restrict__ deg_src,
    int* __restrict__ row_start, int2* __restrict__ edata,
    int E, int nb, int N) {
    __shared__ int cnt[256];
    __shared__ float wsum[256];
    __shared__ int loc[256];
    __shared__ int cur2[256];
    extern __shared__ unsigned int stage[];  // DCAP keys + DCAP floats
    unsigned int* skey = stage;
    float* sw = (float*)(stage + DCAP);

    int k = blockIdx.x;
    int base = offsT[k * PBLK];
    int end = (k + 1 < nb) ? offsT[(k + 1) * PBLK] : E;
    int m = end - base;
    int t = threadIdx.x;
    cnt[t] = 0;
    wsum[t] = 0.f;
    __syncthreads();
    bool staged = (m <= DCAP);
    for (int i = t; i < m; i += 256) {
        unsigned key = pkey[base + i];
        float wv = pw[base + i];
        if (staged) { skey[i] = key; sw[i] = wv; }
        int dl = key >> 24;
        atomicAdd(&cnt[dl], 1);
        atomicAdd(&wsum[dl], wv);
    }
    __syncthreads();
    int v = cnt[t];
    loc[t] = v;
    __syncthreads();
    for (int off = 1; off < 256; off <<= 1) {
        int tv = (t >= off) ? loc[t - off] : 0;
        __syncthreads();
        loc[t] += tv;
        __syncthreads();
    }
    int excl = loc[t] - v;
    loc[t] = excl;       // safe: each thread rewrites only its own slot
    cur2[t] = 0;
    int node = (k << BUCKET_SHIFT) + t;
    if (node < N) row_start[node] = base + excl;
    if (k == 0 && t == 0) row_start[N] = E;
    __syncthreads();
    for (int i = t; i < m; i += 256) {
        unsigned key = staged ? skey[i] : pkey[base + i];
        float wv = staged ? sw[i] : pw[base + i];
        int dl = key >> 24;
        int s = key & 0xFFFFFF;
        int pos = base + loc[dl] + atomicAdd(&cur2[dl], 1);
        float nw = wv * rsqrtf(deg_src[s] * wsum[dl]);
        edata[pos] = make_int2(s, __float_as_int(nw));
    }
}

// out[r] = A[r] @ W  (W is [128][128] row-major). Row-local => in-place safe.
#define GR 16
__global__ __launch_bounds__(256) void gemm128(
    const float* __restrict__ A, const float* __restrict__ W,
    float* __restrict__ out, int n, int nblk) {
    __shared__ float rows[GR][D128];
    const int tid = threadIdx.x;
    const int j = tid & 127;
    const int rg = tid >> 7;
    for (int rb = blockIdx.x; rb < nblk; rb += gridDim.x) {
        const int r0 = rb * GR;
        __syncthreads();
        for (int f = tid; f < GR * 32; f += 256) {
            int rr = f >> 5, ch = f & 31;
            int grow = r0 + rr;
            float4 v = make_float4(0.f, 0.f, 0.f, 0.f);
            if (grow < n) v = ((const float4*)(A + (size_t)grow * D128))[ch];
            ((float4*)&rows[rr][0])[ch] = v;
        }
        __syncthreads();
        float acc[8] = {0.f, 0.f, 0.f, 0.f, 0.f, 0.f, 0.f, 0.f};
        for (int k = 0; k < D128; k += 4) {
            float w0 = W[(k + 0) * D128 + j];
            float w1 = W[(k + 1) * D128 + j];
            float w2 = W[(k + 2) * D128 + j];
            float w3 = W[(k + 3) * D128 + j];
#pragma unroll
            for (int m = 0; m < 8; ++m) {
                float4 r = *((const float4*)&rows[rg + 2 * m][k]);
                acc[m] = fmaf(r.x, w0, acc[m]);
                acc[m] = fmaf(r.y, w1, acc[m]);
                acc[m] = fmaf(r.z, w2, acc[m]);
                acc[m] = fmaf(r.w, w3, acc[m]);
            }
        }
#pragma unroll
        for (int m = 0; m < 8; ++m) {
            int rr = r0 + rg + 2 * m;
            if (rr < n) out[(size_t)rr * D128 + j] = acc[m];
        }
    }
}

// One wave per dst node; 2 edges x 32 float4-chunks per iter, unrolled x2.
__global__ __launch_bounds__(256) void aggregate(
    const float* __restrict__ h, const int* __restrict__ rs,
    const int2* __restrict__ edata,
    const float* __restrict__ bias, float* __restrict__ out, int n) {
    int wave = threadIdx.x >> 6;
    int lane = threadIdx.x & 63;
    int node = blockIdx.x * 4 + wave;
    if (node >= n) return;
    int beg = rs[node], end = rs[node + 1];
    int half = lane >> 5, c = lane & 31;
    float4 acc0 = make_float4(0.f, 0.f, 0.f, 0.f);
    float4 acc1 = make_float4(0.f, 0.f, 0.f, 0.f);
    int i = beg + half;
    for (; i + 2 < end; i += 4) {
        int2 e0 = edata[i];
        int2 e1 = edata[i + 2];
        float4 r0 = ((const float4*)(h + (size_t)e0.x * D128))[c];
        float4 r1 = ((const float4*)(h + (size_t)e1.x * D128))[c];
        float w0 = __int_as_float(e0.y), w1 = __int_as_float(e1.y);
        acc0.x = fmaf(r0.x, w0, acc0.x);
        acc0.y = fmaf(r0.y, w0, acc0.y);
        acc0.z = fmaf(r0.z, w0, acc0.z);
        acc0.w = fmaf(r0.w, w0, acc0.w);
        acc1.x = fmaf(r1.x, w1, acc1.x);
        acc1.y = fmaf(r1.y, w1, acc1.y);
        acc1.z = fmaf(r1.z, w1, acc1.z);
        acc1.w = fmaf(r1.w, w1, acc1.w);
    }
    if (i < end) {
        int2 e0 = edata[i];
        float4 r0 = ((const float4*)(h + (size_t)e0.x * D128))[c];
        float w0 = __int_as_float(e0.y);
        acc0.x = fmaf(r0.x, w0, acc0.x);
        acc0.y = fmaf(r0.y, w0, acc0.y);
        acc0.z = fmaf(r0.z, w0, acc0.z);
        acc0.w = fmaf(r0.w, w0, acc0.w);
    }
    acc0.x += acc1.x; acc0.y += acc1.y; acc0.z += acc1.z; acc0.w += acc1.w;
    acc0.x += __shfl_xor(acc0.x, 32);
    acc0.y += __shfl_xor(acc0.y, 32);
    acc0.z += __shfl_xor(acc0.z, 32);
    acc0.w += __shfl_xor(acc0.w, 32);
    if (half == 0) {
        float4 bb = ((const float4*)bias)[c];
        float4 o;
        o.x = elu1(acc0.x + bb.x);
        o.y = elu1(acc0.y + bb.y);
        o.z = elu1(acc0.z + bb.z);
        o.w = elu1(acc0.w + bb.w);
        ((float4*)(out + (size_t)node * D128))[c] = o;
    }
}

extern "C" void kernel_launch(void* const* d_in, const int* in_sizes, int n_in,
                              void* d_out, int out_size, void* d_ws, size_t ws_size,
                              hipStream_t stream) {
    const float* x   = (const float*)d_in[0];
    const float* ew  = (const float*)d_in[1];
    const float* W   = (const float*)d_in[2];
    const float* b   = (const float*)d_in[3];
    const int*   src = (const int*)d_in[4];
    const int*   dst = (const int*)d_in[5];
    float* out = (float*)d_out;

    const int N = in_sizes[0] / D128;
    const int E = in_sizes[1];
    const int L = in_sizes[2] / (D128 * D128);
    const int nb = (N + 255) >> BUCKET_SHIFT;       // coarse buckets
    const int hlen = nb * PBLK;                     // transposed hist length

    char* ws = (char*)d_ws;
    size_t off = 0;
    auto take = [&](size_t bytes) {
        void* p = ws + off;
        off = (off + bytes + 255) & ~(size_t)255;
        return p;
    };
    float* deg_src = (float*)take((size_t)N * 4);
    int*   histT   = (int*)take((size_t)hlen * 4);
    int*   offsT   = (int*)take((size_t)hlen * 4);
    int*   bsums   = (int*)take(512 * 4);
    int*   rstart  = (int*)take((size_t)(N + 1) * 4);
    int2*  edata   = (int2*)take((size_t)E * 8);
    float* B0      = (float*)take((size_t)N * D128 * 4);
    // pkey/pw alias B0: dead before gemm0 writes B0.
    unsigned int* pkey = (unsigned int*)B0;
    float*        pw   = (float*)(B0 + E);

    hipMemsetAsync(deg_src, 0, (size_t)N * 4, stream);

    const int eb = (E + 255) / 256;
    const int chunk = (E + PBLK - 1) / PBLK;
    const int sb = (hlen + 255) / 256;              // <= 512
    const size_t part_lds = (size_t)nb * 4;
    const size_t dcap_lds = (size_t)DCAP * 8;

    deg_src_hist<<<eb, 256, 0, stream>>>(src, ew, deg_src, E);
    part_hist<<<PBLK, 256, part_lds, stream>>>(dst, histT, E, nb, chunk);
    scan_block<<<sb, 256, 0, stream>>>(histT, offsT, bsums, hlen);
    scan_sums<<<1, 512, 0, stream>>>(bsums, sb);
    scan_add<<<sb, 256, 0, stream>>>(offsT, bsums, hlen);
    part_scatter<<<PBLK, 256, part_lds, stream>>>(src, dst, ew, offsT,
                                                  pkey, pw, E, nb, chunk);
    bucket_build<<<nb, 256, dcap_lds, stream>>>(pkey, pw, offsT, deg_src,
                                                rstart, edata, E, nb, N);

    const int nblk = (N + GR - 1) / GR;
    const int gemm_grid = nblk < 2048 ? nblk : 2048;
    const int agg_grid = (N + 3) / 4;

    // layer 0: x --gemm--> B0 --agg--> out
    gemm128<<<gemm_grid, 256, 0, stream>>>(x, W, B0, N, nblk);
    aggregate<<<agg_grid, 256, 0, stream>>>(B0, rstart, edata, b, out, N);
    if (L > 1) {
        gemm128<<<gemm_grid, 256, 0, stream>>>(out, W + D128 * D128, out, N, nblk);
        aggregate<<<agg_grid, 256, 0, stream>>>(out, rstart, edata, b + D128, B0, N);
    }
    if (L > 2) {
        gemm128<<<gemm_grid, 256, 0, stream>>>(B0, W + 2 * D128 * D128, B0, N, nblk);
        aggregate<<<agg_grid, 256, 0, stream>>>(B0, rstart, edata, b + 2 * D128, out, N);
    }
}

// Round 4
// 619.331 us; speedup vs baseline: 1.4197x; 1.1438x over previous
//
#include <hip/hip_runtime.h>
#include <hip/hip_bf16.h>

// HeteroGCNConv: 3-layer GCN, N=100000, E=1600000, D=128, f32.
// R3: (1) deg_src via src-radix-partition + LDS bucket sum (no global atomics
//     anywhere); (2) fused aggregate+GEMM kernels for layer boundaries;
//     (3) gather loop unrolled x4.

#define D128 128
#define PBLK 256          // partition blocks (pass A/C)
#define BUCKET_SHIFT 8
#define DCAP 7168         // staged edges per bucket in pass D (57KB LDS)
#define GR 16

__device__ __forceinline__ float elu1(float x) {
    return x > 0.f ? x : (expf(x) - 1.f);
}

// Pass A: per-block coarse-bucket histograms for BOTH dst and src.
__global__ __launch_bounds__(256) void part_hist2(
    const int* __restrict__ src, const int* __restrict__ dst,
    int* __restrict__ histT2, int E, int nb, int chunk, int hlen) {
    extern __shared__ int sh[];  // 2*nb ints
    for (int i = threadIdx.x; i < 2 * nb; i += 256) sh[i] = 0;
    __syncthreads();
    int b = blockIdx.x;
    int beg = b * chunk, end = min(E, beg + chunk);
    for (int e = beg + threadIdx.x; e < end; e += 256) {
        atomicAdd(&sh[dst[e] >> BUCKET_SHIFT], 1);
        atomicAdd(&sh[nb + (src[e] >> BUCKET_SHIFT)], 1);
    }
    __syncthreads();
    for (int i = threadIdx.x; i < nb; i += 256)
        histT2[i * PBLK + b] = sh[i];
    for (int i = threadIdx.x; i < nb; i += 256)
        histT2[hlen + i * PBLK + b] = sh[nb + i];
}

// Hierarchical exclusive scan (n <= 262144).
__global__ __launch_bounds__(256) void scan_block(
    const int* __restrict__ in, int* __restrict__ out,
    int* __restrict__ blockSums, int n) {
    __shared__ int tmp[256];
    int gid = blockIdx.x * 256 + threadIdx.x;
    int v = (gid < n) ? in[gid] : 0;
    tmp[threadIdx.x] = v;
    __syncthreads();
    for (int off = 1; off < 256; off <<= 1) {
        int t = (threadIdx.x >= off) ? tmp[threadIdx.x - off] : 0;
        __syncthreads();
        tmp[threadIdx.x] += t;
        __syncthreads();
    }
    if (gid < n) out[gid] = tmp[threadIdx.x] - v;  // exclusive
    if (threadIdx.x == 255) blockSums[blockIdx.x] = tmp[255];
}

__global__ __launch_bounds__(1024) void scan_sums(int* __restrict__ bsums, int nb) {
    __shared__ int tmp[1024];
    int v = (threadIdx.x < nb) ? bsums[threadIdx.x] : 0;
    tmp[threadIdx.x] = v;
    __syncthreads();
    for (int off = 1; off < 1024; off <<= 1) {
        int t = (threadIdx.x >= off) ? tmp[threadIdx.x - off] : 0;
        __syncthreads();
        tmp[threadIdx.x] += t;
        __syncthreads();
    }
    if (threadIdx.x < nb) bsums[threadIdx.x] = tmp[threadIdx.x] - v;  // exclusive
}

__global__ __launch_bounds__(256) void scan_add(
    int* __restrict__ out, const int* __restrict__ bsums, int n) {
    int gid = blockIdx.x * 256 + threadIdx.x;
    if (gid < n) out[gid] += bsums[blockIdx.x];
}

// Pass C: stable partition by dst (pkeyD/pwD) AND by src (skw), one pass.
__global__ __launch_bounds__(256) void part_scatter2(
    const int* __restrict__ src, const int* __restrict__ dst,
    const float* __restrict__ w, const int* __restrict__ offsT2,
    unsigned int* __restrict__ pkeyD, float* __restrict__ pwD,
    int2* __restrict__ skw, int E, int nb, int chunk, int hlen) {
    extern __shared__ int cur[];  // 2*nb ints
    int b = blockIdx.x;
    for (int i = threadIdx.x; i < nb; i += 256)
        cur[i] = offsT2[i * PBLK + b];
    for (int i = threadIdx.x; i < nb; i += 256)
        cur[nb + i] = offsT2[hlen + i * PBLK + b] - E;
    __syncthreads();
    int beg = b * chunk, end = min(E, beg + chunk);
    for (int e = beg + threadIdx.x; e < end; e += 256) {
        int d = dst[e];
        int s = src[e];
        float wv = w[e];
        int kd = d >> BUCKET_SHIFT;
        int pos = atomicAdd(&cur[kd], 1);
        pkeyD[pos] = (unsigned)s | ((unsigned)(d & 255) << 24);
        pwD[pos] = wv;
        int ks = s >> BUCKET_SHIFT;
        int posS = atomicAdd(&cur[nb + ks], 1);
        skw[posS] = make_int2(s & 255, __float_as_int(wv));
    }
}

// Weighted out-degree per node: one block per src bucket, LDS float sums.
__global__ __launch_bounds__(256) void bucket_sumS(
    const int2* __restrict__ skw, const int* __restrict__ offsT2,
    float* __restrict__ deg_src, int E, int nb, int N, int hlen) {
    __shared__ float wsum[256];
    int k = blockIdx.x;
    int base = offsT2[hlen + k * PBLK] - E;
    int end = (k + 1 < nb) ? (offsT2[hlen + (k + 1) * PBLK] - E) : E;
    int t = threadIdx.x;
    wsum[t] = 0.f;
    __syncthreads();
    for (int i = base + t; i < end; i += 256) {
        int2 v = skw[i];
        atomicAdd(&wsum[v.x], __int_as_float(v.y));
    }
    __syncthreads();
    int node = (k << BUCKET_SHIFT) + t;
    if (node < N) deg_src[node] = wsum[t];
}

// Pass D: one block per dst bucket. LDS histogram -> per-node counts +
// weighted in-degree; LDS scan -> row_start; reorder; write edata{src,nw}.
__global__ __launch_bounds__(256) void bucket_build(
    const unsigned int* __restrict__ pkey, const float* __restrict__ pw,
    const int* __restrict__ offsT, const float* __restrict__ deg_src,
    int* __restrict__ row_start, int2* __restrict__ edata,
    int E, int nb, int N) {
    __shared__ int cnt[256];
    __shared__ float wsum[256];
    __shared__ int loc[256];
    __shared__ int cur2[256];
    extern __shared__ unsigned int stage[];  // DCAP keys + DCAP floats
    unsigned int* skey = stage;
    float* sw = (float*)(stage + DCAP);

    int k = blockIdx.x;
    int base = offsT[k * PBLK];
    int end = (k + 1 < nb) ? offsT[(k + 1) * PBLK] : E;
    int m = end - base;
    int t = threadIdx.x;
    cnt[t] = 0;
    wsum[t] = 0.f;
    __syncthreads();
    bool staged = (m <= DCAP);
    for (int i = t; i < m; i += 256) {
        unsigned key = pkey[base + i];
        float wv = pw[base + i];
        if (staged) { skey[i] = key; sw[i] = wv; }
        int dl = key >> 24;
        atomicAdd(&cnt[dl], 1);
        atomicAdd(&wsum[dl], wv);
    }
    __syncthreads();
    int v = cnt[t];
    loc[t] = v;
    __syncthreads();
    for (int off = 1; off < 256; off <<= 1) {
        int tv = (t >= off) ? loc[t - off] : 0;
        __syncthreads();
        loc[t] += tv;
        __syncthreads();
    }
    int excl = loc[t] - v;
    loc[t] = excl;
    cur2[t] = 0;
    int node = (k << BUCKET_SHIFT) + t;
    if (node < N) row_start[node] = base + excl;
    if (k == 0 && t == 0) row_start[N] = E;
    __syncthreads();
    for (int i = t; i < m; i += 256) {
        unsigned key = staged ? skey[i] : pkey[base + i];
        float wv = staged ? sw[i] : pw[base + i];
        int dl = key >> 24;
        int s = key & 0xFFFFFF;
        int pos = base + loc[dl] + atomicAdd(&cur2[dl], 1);
        float nw = wv * rsqrtf(deg_src[s] * wsum[dl]);
        edata[pos] = make_int2(s, __float_as_int(nw));
    }
}

// out[r] = A[r] @ W  (W is [128][128] row-major). Row-local => in-place safe.
__global__ __launch_bounds__(256) void gemm128(
    const float* __restrict__ A, const float* __restrict__ W,
    float* __restrict__ out, int n, int nblk) {
    __shared__ float rows[GR][D128];
    const int tid = threadIdx.x;
    const int j = tid & 127;
    const int rg = tid >> 7;
    for (int rb = blockIdx.x; rb < nblk; rb += gridDim.x) {
        const int r0 = rb * GR;
        __syncthreads();
        for (int f = tid; f < GR * 32; f += 256) {
            int rr = f >> 5, ch = f & 31;
            int grow = r0 + rr;
            float4 v = make_float4(0.f, 0.f, 0.f, 0.f);
            if (grow < n) v = ((const float4*)(A + (size_t)grow * D128))[ch];
            ((float4*)&rows[rr][0])[ch] = v;
        }
        __syncthreads();
        float acc[8] = {0.f, 0.f, 0.f, 0.f, 0.f, 0.f, 0.f, 0.f};
        for (int k = 0; k < D128; k += 4) {
            float w0 = W[(k + 0) * D128 + j];
            float w1 = W[(k + 1) * D128 + j];
            float w2 = W[(k + 2) * D128 + j];
            float w3 = W[(k + 3) * D128 + j];
#pragma unroll
            for (int m = 0; m < 8; ++m) {
                float4 r = *((const float4*)&rows[rg + 2 * m][k]);
                acc[m] = fmaf(r.x, w0, acc[m]);
                acc[m] = fmaf(r.y, w1, acc[m]);
                acc[m] = fmaf(r.z, w2, acc[m]);
                acc[m] = fmaf(r.w, w3, acc[m]);
            }
        }
#pragma unroll
        for (int m = 0; m < 8; ++m) {
            int rr = r0 + rg + 2 * m;
            if (rr < n) out[(size_t)rr * D128 + j] = acc[m];
        }
    }
}

// Gather-aggregate one node into (half==0) lanes' float4 acc. Unrolled x4.
__device__ __forceinline__ float4 agg_node(
    const float* __restrict__ h, const int2* __restrict__ edata,
    int beg, int end, int half, int c) {
    float4 a0 = make_float4(0.f, 0.f, 0.f, 0.f);
    float4 a1 = a0, a2 = a0, a3 = a0;
    int i = beg + half;
    for (; i + 6 < end; i += 8) {
        int2 e0 = edata[i];
        int2 e1 = edata[i + 2];
        int2 e2 = edata[i + 4];
        int2 e3 = edata[i + 6];
        float4 r0 = ((const float4*)(h + (size_t)e0.x * D128))[c];
        float4 r1 = ((const float4*)(h + (size_t)e1.x * D128))[c];
        float4 r2 = ((const float4*)(h + (size_t)e2.x * D128))[c];
        float4 r3 = ((const float4*)(h + (size_t)e3.x * D128))[c];
        float w0 = __int_as_float(e0.y), w1 = __int_as_float(e1.y);
        float w2 = __int_as_float(e2.y), w3 = __int_as_float(e3.y);
        a0.x = fmaf(r0.x, w0, a0.x); a0.y = fmaf(r0.y, w0, a0.y);
        a0.z = fmaf(r0.z, w0, a0.z); a0.w = fmaf(r0.w, w0, a0.w);
        a1.x = fmaf(r1.x, w1, a1.x); a1.y = fmaf(r1.y, w1, a1.y);
        a1.z = fmaf(r1.z, w1, a1.z); a1.w = fmaf(r1.w, w1, a1.w);
        a2.x = fmaf(r2.x, w2, a2.x); a2.y = fmaf(r2.y, w2, a2.y);
        a2.z = fmaf(r2.z, w2, a2.z); a2.w = fmaf(r2.w, w2, a2.w);
        a3.x = fmaf(r3.x, w3, a3.x); a3.y = fmaf(r3.y, w3, a3.y);
        a3.z = fmaf(r3.z, w3, a3.z); a3.w = fmaf(r3.w, w3, a3.w);
    }
    for (; i < end; i += 2) {
        int2 e0 = edata[i];
        float4 r0 = ((const float4*)(h + (size_t)e0.x * D128))[c];
        float w0 = __int_as_float(e0.y);
        a0.x = fmaf(r0.x, w0, a0.x); a0.y = fmaf(r0.y, w0, a0.y);
        a0.z = fmaf(r0.z, w0, a0.z); a0.w = fmaf(r0.w, w0, a0.w);
    }
    a0.x += a1.x + a2.x + a3.x;
    a0.y += a1.y + a2.y + a3.y;
    a0.z += a1.z + a2.z + a3.z;
    a0.w += a1.w + a2.w + a3.w;
    a0.x += __shfl_xor(a0.x, 32);
    a0.y += __shfl_xor(a0.y, 32);
    a0.z += __shfl_xor(a0.z, 32);
    a0.w += __shfl_xor(a0.w, 32);
    return a0;
}

// Standalone aggregate (+bias, ELU): one wave per dst node.
__global__ __launch_bounds__(256) void aggregate(
    const float* __restrict__ h, const int* __restrict__ rs,
    const int2* __restrict__ edata,
    const float* __restrict__ bias, float* __restrict__ out, int n) {
    int wave = threadIdx.x >> 6;
    int lane = threadIdx.x & 63;
    int node = blockIdx.x * 4 + wave;
    if (node >= n) return;
    int half = lane >> 5, c = lane & 31;
    float4 a = agg_node(h, edata, rs[node], rs[node + 1], half, c);
    if (half == 0) {
        float4 bb = ((const float4*)bias)[c];
        float4 o;
        o.x = elu1(a.x + bb.x);
        o.y = elu1(a.y + bb.y);
        o.z = elu1(a.z + bb.z);
        o.w = elu1(a.w + bb.w);
        ((float4*)(out + (size_t)node * D128))[c] = o;
    }
}

// Fused: rows[] = ELU(aggregate(h) + bias_prev), then out = rows @ Wnext.
__global__ __launch_bounds__(256) void agg_gemm(
    const float* __restrict__ h, const int* __restrict__ rs,
    const int2* __restrict__ edata, const float* __restrict__ bias,
    const float* __restrict__ W, float* __restrict__ out, int n, int nblk) {
    __shared__ float rows[GR][D128];
    const int tid = threadIdx.x;
    const int wave = tid >> 6;
    const int lane = tid & 63;
    const int half = lane >> 5;
    const int c = lane & 31;
    const int j = tid & 127;
    const int rg = tid >> 7;
    for (int rb = blockIdx.x; rb < nblk; rb += gridDim.x) {
        const int r0 = rb * GR;
        __syncthreads();  // protect rows[] from previous iteration's readers
#pragma unroll
        for (int q = 0; q < 4; ++q) {
            int rr = wave * 4 + q;
            int node = r0 + rr;
            if (node < n) {
                float4 a = agg_node(h, edata, rs[node], rs[node + 1], half, c);
                if (half == 0) {
                    float4 bb = ((const float4*)bias)[c];
                    float4 o;
                    o.x = elu1(a.x + bb.x);
                    o.y = elu1(a.y + bb.y);
                    o.z = elu1(a.z + bb.z);
                    o.w = elu1(a.w + bb.w);
                    ((float4*)&rows[rr][0])[c] = o;
                }
            } else if (half == 0) {
                ((float4*)&rows[rr][0])[c] = make_float4(0.f, 0.f, 0.f, 0.f);
            }
        }
        __syncthreads();
        float acc[8] = {0.f, 0.f, 0.f, 0.f, 0.f, 0.f, 0.f, 0.f};
        for (int k = 0; k < D128; k += 4) {
            float w0 = W[(k + 0) * D128 + j];
            float w1 = W[(k + 1) * D128 + j];
            float w2 = W[(k + 2) * D128 + j];
            float w3 = W[(k + 3) * D128 + j];
#pragma unroll
            for (int m = 0; m < 8; ++m) {
                float4 r = *((const float4*)&rows[rg + 2 * m][k]);
                acc[m] = fmaf(r.x, w0, acc[m]);
                acc[m] = fmaf(r.y, w1, acc[m]);
                acc[m] = fmaf(r.z, w2, acc[m]);
                acc[m] = fmaf(r.w, w3, acc[m]);
            }
        }
#pragma unroll
        for (int m = 0; m < 8; ++m) {
            int rr = r0 + rg + 2 * m;
            if (rr < n) out[(size_t)rr * D128 + j] = acc[m];
        }
    }
}

extern "C" void kernel_launch(void* const* d_in, const int* in_sizes, int n_in,
                              void* d_out, int out_size, void* d_ws, size_t ws_size,
                              hipStream_t stream) {
    const float* x   = (const float*)d_in[0];
    const float* ew  = (const float*)d_in[1];
    const float* W   = (const float*)d_in[2];
    const float* b   = (const float*)d_in[3];
    const int*   src = (const int*)d_in[4];
    const int*   dst = (const int*)d_in[5];
    float* out = (float*)d_out;

    const int N = in_sizes[0] / D128;
    const int E = in_sizes[1];
    const int L = in_sizes[2] / (D128 * D128);   // == 3 here
    const int nb = (N + 255) >> BUCKET_SHIFT;
    const int hlen = nb * PBLK;

    char* ws = (char*)d_ws;
    size_t off = 0;
    auto take = [&](size_t bytes) {
        void* p = ws + off;
        off = (off + bytes + 255) & ~(size_t)255;
        return p;
    };
    float* deg_src = (float*)take((size_t)N * 4);
    int*   histT2  = (int*)take((size_t)2 * hlen * 4);
    int*   offsT2  = (int*)take((size_t)2 * hlen * 4);
    int*   bsums   = (int*)take(1024 * 4);
    int*   rstart  = (int*)take((size_t)(N + 1) * 4);
    int2*  edata   = (int2*)take((size_t)E * 8);
    float* B0      = (float*)take((size_t)N * D128 * 4);
    // partition scratch aliases B0 (dead before gemm0 writes B0):
    unsigned int* pkeyD = (unsigned int*)B0;          // E * 4
    float*        pwD   = (float*)(B0 + E);           // E * 4
    int2*         skw   = (int2*)(B0 + 2 * (size_t)E); // E * 8

    const int chunk = (E + PBLK - 1) / PBLK;
    const int sb2 = (2 * hlen + 255) / 256;          // <= 1024
    const size_t part_lds = (size_t)2 * nb * 4;
    const size_t dcap_lds = (size_t)DCAP * 8;

    part_hist2<<<PBLK, 256, part_lds, stream>>>(src, dst, histT2, E, nb, chunk, hlen);
    scan_block<<<sb2, 256, 0, stream>>>(histT2, offsT2, bsums, 2 * hlen);
    scan_sums<<<1, 1024, 0, stream>>>(bsums, sb2);
    scan_add<<<sb2, 256, 0, stream>>>(offsT2, bsums, 2 * hlen);
    part_scatter2<<<PBLK, 256, part_lds, stream>>>(src, dst, ew, offsT2,
                                                   pkeyD, pwD, skw, E, nb, chunk, hlen);
    bucket_sumS<<<nb, 256, 0, stream>>>(skw, offsT2, deg_src, E, nb, N, hlen);
    bucket_build<<<nb, 256, dcap_lds, stream>>>(pkeyD, pwD, offsT2, deg_src,
                                                rstart, edata, E, nb, N);

    const int nblk = (N + GR - 1) / GR;
    const int gemm_grid = nblk < 2048 ? nblk : 2048;
    const int agg_grid = (N + 3) / 4;

    // layer 0 transform: x @ W0 -> B0
    gemm128<<<gemm_grid, 256, 0, stream>>>(x, W, B0, N, nblk);
    // agg0 (+b0, ELU) fused with layer-1 transform: -> out
    agg_gemm<<<gemm_grid, 256, 0, stream>>>(B0, rstart, edata, b,
                                            W + D128 * D128, out, N, nblk);
    // agg1 (+b1, ELU) fused with layer-2 transform: -> B0
    agg_gemm<<<gemm_grid, 256, 0, stream>>>(out, rstart, edata, b + D128,
                                            W + 2 * D128 * D128, B0, N, nblk);
    // final agg2 (+b2, ELU) -> out
    aggregate<<<agg_grid, 256, 0, stream>>>(B0, rstart, edata, b + 2 * D128, out, N);
}